// Round 1
// baseline (104.104 us; speedup 1.0000x reference)
//
#include <hip/hip_runtime.h>
#include <cstdint>
#include <cstddef>

// Problem constants (fixed by the reference)
constexpr int Bc = 4, Tc = 4096, Ec = 1024, Hc = 16, Dc = 64, CHc = 64;
constexpr int NSEG = 4;               // segments per sequence (parallel chunks of the scan)
constexpr int SEGT = Tc / NSEG;       // 1024 tokens per segment
constexpr int NCHUNK = SEGT / CHc;    // 16 chunks per segment
constexpr int LP = 72;                // padded LDS row stride in bf16 elems (144B -> conflict-free b128)

typedef __attribute__((ext_vector_type(8))) short short8;  // 8 bf16 (4 VGPRs) MFMA A/B frag
typedef __attribute__((ext_vector_type(4))) float f32x4;   // MFMA C/D frag

__device__ __forceinline__ unsigned short f2bf(float f) {
  union { float f; unsigned int u; } v; v.f = f;
  return (unsigned short)((v.u + 0x7FFFu + ((v.u >> 16) & 1u)) >> 16);  // RNE
}
__device__ __forceinline__ float phi_elu1(float x) {   // elu(x)+1
  return x > 0.f ? x + 1.f : __expf(x);
}
__device__ __forceinline__ short8 ld8(const unsigned short* p) {
  return *reinterpret_cast<const short8*>(p);
}
__device__ __forceinline__ void st8(unsigned short* p, short8 v) {
  *reinterpret_cast<short8*>(p) = v;
}

#define MFMA_B16(a, b, c) __builtin_amdgcn_mfma_f32_16x16x32_bf16((a), (b), (c), 0, 0, 0)

// ---------------- pass0: W[d][e] fp32 -> WT[e][d] bf16 (q,k,v,o) ----------------
__global__ void prep_weights(const float* __restrict__ Wq, const float* __restrict__ Wk,
                             const float* __restrict__ Wv, const float* __restrict__ Wo,
                             unsigned short* __restrict__ wT) {
  int tid = blockIdx.x * blockDim.x + threadIdx.x;
  if (tid >= 4 * Dc * Dc) return;
  int m = tid >> 12, i = tid & 4095, d = i >> 6, e = i & 63;
  const float* W = (m == 0) ? Wq : (m == 1) ? Wk : (m == 2) ? Wv : Wo;
  wT[m * 4096 + e * 64 + d] = f2bf(W[d * 64 + e]);
}

// ---------------- pass1: per-(bh,seg) KV = sum_t phi(k)[t]^T v[t]  -> ws fp32 ----------------
__global__ __launch_bounds__(256) void pass1_kvseg(
    const float* __restrict__ x, const unsigned short* __restrict__ wT,
    float* __restrict__ kvseg) {
  __shared__ unsigned short s_xc[64 * LP];
  __shared__ unsigned short s_kT[64 * LP];
  __shared__ unsigned short s_vT[64 * LP];

  const int tid = threadIdx.x;
  const int w = tid >> 6, lane = tid & 63, lr = lane & 15, lq = lane >> 4;
  const int bh = blockIdx.x, sg = blockIdx.y;
  const int b = bh >> 4, h = bh & 15;
  const float* xbase = x + ((size_t)b * Tc + (size_t)sg * SEGT) * Ec + h * Dc;
  const unsigned short* wkT = wT + 4096;
  const unsigned short* wvT = wT + 2 * 4096;
  const int sr = tid >> 2, sc = tid & 3;
  const int arow = (w * 16 + lr) * LP;

  const f32x4 zero4 = {0.f, 0.f, 0.f, 0.f};
  f32x4 sacc[4] = {zero4, zero4, zero4, zero4};  // ST[d][e] tiles, rows d = w*16..+15

  // loop-invariant weight A-frags: WkT/WvT rows (w*16+lr)
  short8 awk[2], awv[2];
#pragma unroll
  for (int kk = 0; kk < 2; ++kk) {
    awk[kk] = ld8(wkT + (w * 16 + lr) * 64 + kk * 32 + lq * 8);
    awv[kk] = ld8(wvT + (w * 16 + lr) * 64 + kk * 32 + lq * 8);
  }

  for (int ci = 0; ci < NCHUNK; ++ci) {
    {  // stage x chunk [64 tok x 64 d] fp32 -> bf16 LDS (row-major)
      const float* xr = xbase + (size_t)(ci * CHc + sr) * Ec + sc * 16;
      const float4* xf = reinterpret_cast<const float4*>(xr);
      float4 f0 = xf[0], f1 = xf[1], f2 = xf[2], f3 = xf[3];
      union { unsigned short us[16]; short8 v[2]; } pk;
      pk.us[0] = f2bf(f0.x);  pk.us[1] = f2bf(f0.y);  pk.us[2] = f2bf(f0.z);  pk.us[3] = f2bf(f0.w);
      pk.us[4] = f2bf(f1.x);  pk.us[5] = f2bf(f1.y);  pk.us[6] = f2bf(f1.z);  pk.us[7] = f2bf(f1.w);
      pk.us[8] = f2bf(f2.x);  pk.us[9] = f2bf(f2.y);  pk.us[10] = f2bf(f2.z); pk.us[11] = f2bf(f2.w);
      pk.us[12] = f2bf(f3.x); pk.us[13] = f2bf(f3.y); pk.us[14] = f2bf(f3.z); pk.us[15] = f2bf(f3.w);
      unsigned short* dst = &s_xc[sr * LP + sc * 16];
      st8(dst, pk.v[0]); st8(dst + 8, pk.v[1]);
    }
    __syncthreads();  // B0

    // transposed-form projections: kT[e][t] = phi(sum_d WkT[e][d] x[t][d]), vT[d][t]
    f32x4 ak[4] = {zero4, zero4, zero4, zero4};
    f32x4 av[4] = {zero4, zero4, zero4, zero4};
#pragma unroll
    for (int c = 0; c < 4; ++c) {
#pragma unroll
      for (int kk = 0; kk < 2; ++kk) {
        short8 bx = ld8(&s_xc[(c * 16 + lr) * LP + kk * 32 + lq * 8]);
        ak[c] = MFMA_B16(awk[kk], bx, ak[c]);
        av[c] = MFMA_B16(awv[kk], bx, av[c]);
      }
    }
#pragma unroll
    for (int c = 0; c < 4; ++c) {
#pragma unroll
      for (int j = 0; j < 4; ++j) {
        int r = w * 16 + lq * 4 + j;
        s_kT[r * LP + c * 16 + lr] = f2bf(phi_elu1(ak[c][j]));
        s_vT[r * LP + c * 16 + lr] = f2bf(av[c][j]);
      }
    }
    __syncthreads();  // B1

    // state update: ST[d][e] += sum_t vT[d][t] * k[t][e]   (A=vT rows, B from kT storage)
    short8 avt[2];
#pragma unroll
    for (int kk = 0; kk < 2; ++kk)
      avt[kk] = ld8(&s_vT[arow + kk * 32 + lq * 8]);
#pragma unroll
    for (int c = 0; c < 4; ++c) {
#pragma unroll
      for (int kk = 0; kk < 2; ++kk) {
        short8 bk = ld8(&s_kT[(c * 16 + lr) * LP + kk * 32 + lq * 8]);
        sacc[c] = MFMA_B16(avt[kk], bk, sacc[c]);
      }
    }
    // next stage-write of s_xc is gated by B0 of next iter; kT/vT reads done before it
  }

  float* dst = kvseg + ((size_t)(bh * NSEG + sg)) * 4096;
#pragma unroll
  for (int c = 0; c < 4; ++c)
#pragma unroll
    for (int j = 0; j < 4; ++j)
      dst[(w * 16 + lq * 4 + j) * 64 + c * 16 + lr] = sacc[c][j];
}

// ---------------- pass3: main recurrence per (bh,seg) ----------------
__global__ __launch_bounds__(256) void pass3_main(
    const float* __restrict__ x, const unsigned short* __restrict__ wT,
    const float* __restrict__ kvseg, float* __restrict__ out) {
  __shared__ unsigned short s_xo[64 * LP];  // xc, later o
  __shared__ unsigned short s_q [64 * LP];  // q[t][e]
  __shared__ unsigned short s_k [64 * LP];  // k[t][e]
  __shared__ unsigned short s_kT[64 * LP];  // k^T[e][t]
  __shared__ unsigned short s_vT[64 * LP];  // v^T[d][t]
  __shared__ unsigned short s_at[64 * LP];  // masked attn[t][t']
  __shared__ unsigned short s_Sb[64 * LP];  // ST[d][e] bf16 snapshot (pre-update)

  const int tid = threadIdx.x;
  const int w = tid >> 6, lane = tid & 63, lr = lane & 15, lq = lane >> 4;
  const int bh = blockIdx.x, sg = blockIdx.y;
  const int b = bh >> 4, h = bh & 15;
  const float* xbase = x + ((size_t)b * Tc + (size_t)sg * SEGT) * Ec + h * Dc;
  float* obase = out + ((size_t)b * Tc + (size_t)sg * SEGT) * Ec + h * Dc;
  const unsigned short* wqT = wT;
  const unsigned short* wkT = wT + 4096;
  const unsigned short* wvT = wT + 2 * 4096;
  const unsigned short* woT = wT + 3 * 4096;
  const int sr = tid >> 2, sc = tid & 3;
  const int arow = (w * 16 + lr) * LP;

  const f32x4 zero4 = {0.f, 0.f, 0.f, 0.f};
  // S state (ST[d][e]) in fp32 acc regs; init = sum of previous segments' KV
  f32x4 sacc[4] = {zero4, zero4, zero4, zero4};
  for (int sp = 0; sp < sg; ++sp) {
    const float* src = kvseg + ((size_t)(bh * NSEG + sp)) * 4096;
#pragma unroll
    for (int c = 0; c < 4; ++c)
#pragma unroll
      for (int j = 0; j < 4; ++j)
        sacc[c][j] += src[(w * 16 + lq * 4 + j) * 64 + c * 16 + lr];
  }

  short8 awv[2];  // WvT A-frags (loop-invariant)
#pragma unroll
  for (int kk = 0; kk < 2; ++kk)
    awv[kk] = ld8(wvT + (w * 16 + lr) * 64 + kk * 32 + lq * 8);

  for (int ci = 0; ci < NCHUNK; ++ci) {
    {  // stage x chunk -> s_xo bf16
      const float* xr = xbase + (size_t)(ci * CHc + sr) * Ec + sc * 16;
      const float4* xf = reinterpret_cast<const float4*>(xr);
      float4 f0 = xf[0], f1 = xf[1], f2 = xf[2], f3 = xf[3];
      union { unsigned short us[16]; short8 v[2]; } pk;
      pk.us[0] = f2bf(f0.x);  pk.us[1] = f2bf(f0.y);  pk.us[2] = f2bf(f0.z);  pk.us[3] = f2bf(f0.w);
      pk.us[4] = f2bf(f1.x);  pk.us[5] = f2bf(f1.y);  pk.us[6] = f2bf(f1.z);  pk.us[7] = f2bf(f1.w);
      pk.us[8] = f2bf(f2.x);  pk.us[9] = f2bf(f2.y);  pk.us[10] = f2bf(f2.z); pk.us[11] = f2bf(f2.w);
      pk.us[12] = f2bf(f3.x); pk.us[13] = f2bf(f3.y); pk.us[14] = f2bf(f3.z); pk.us[15] = f2bf(f3.w);
      unsigned short* dst = &s_xo[sr * LP + sc * 16];
      st8(dst, pk.v[0]); st8(dst + 8, pk.v[1]);
    }
    __syncthreads();  // B0

    // ---- stage A: q = phi(x Wq), k = phi(x Wk) (normal form), vT (transposed form) ----
    short8 ax[2];
    ax[0] = ld8(&s_xo[arow + 0 + lq * 8]);
    ax[1] = ld8(&s_xo[arow + 32 + lq * 8]);
    f32x4 aq[4]  = {zero4, zero4, zero4, zero4};
    f32x4 ack[4] = {zero4, zero4, zero4, zero4};
    f32x4 acv[4] = {zero4, zero4, zero4, zero4};
#pragma unroll
    for (int c = 0; c < 4; ++c) {
      const int br = c * 16 + lr;
#pragma unroll
      for (int kk = 0; kk < 2; ++kk) {
        short8 bwq = ld8(wqT + br * 64 + kk * 32 + lq * 8);
        aq[c] = MFMA_B16(ax[kk], bwq, aq[c]);
        short8 bwk = ld8(wkT + br * 64 + kk * 32 + lq * 8);
        ack[c] = MFMA_B16(ax[kk], bwk, ack[c]);
        short8 bx = ld8(&s_xo[br * LP + kk * 32 + lq * 8]);
        acv[c] = MFMA_B16(awv[kk], bx, acv[c]);
      }
    }
#pragma unroll
    for (int c = 0; c < 4; ++c) {
#pragma unroll
      for (int j = 0; j < 4; ++j) {
        int r = w * 16 + lq * 4 + j;
        float qv = phi_elu1(aq[c][j]);
        float kv2 = phi_elu1(ack[c][j]);
        s_q[r * LP + c * 16 + lr] = f2bf(qv);
        s_k[r * LP + c * 16 + lr] = f2bf(kv2);
        s_kT[(c * 16 + lr) * LP + r] = f2bf(kv2);       // scatter transpose
        s_vT[r * LP + c * 16 + lr] = f2bf(acv[c][j]);   // vT rows are d
        s_Sb[r * LP + c * 16 + lr] = f2bf(sacc[c][j]);  // pre-update state snapshot
      }
    }
    __syncthreads();  // B1

    // ---- stage B: attn = mask(q k^T); state update ST += v^T k ----
    short8 a_q[2], a_v[2];
#pragma unroll
    for (int kk = 0; kk < 2; ++kk) {
      a_q[kk] = ld8(&s_q[arow + kk * 32 + lq * 8]);
      a_v[kk] = ld8(&s_vT[arow + kk * 32 + lq * 8]);
    }
    f32x4 aat[4] = {zero4, zero4, zero4, zero4};
#pragma unroll
    for (int c = 0; c < 4; ++c) {
      const int br = (c * 16 + lr) * LP;
#pragma unroll
      for (int kk = 0; kk < 2; ++kk) {
        aat[c]  = MFMA_B16(a_q[kk], ld8(&s_k[br + kk * 32 + lq * 8]), aat[c]);
        sacc[c] = MFMA_B16(a_v[kk], ld8(&s_kT[br + kk * 32 + lq * 8]), sacc[c]);
      }
    }
#pragma unroll
    for (int c = 0; c < 4; ++c) {
#pragma unroll
      for (int j = 0; j < 4; ++j) {
        int t = w * 16 + lq * 4 + j, tp = c * 16 + lr;
        s_at[t * LP + tp] = f2bf((tp <= t) ? aat[c][j] : 0.f);  // causal tril incl diag
      }
    }
    __syncthreads();  // B2

    // ---- stage C: o = attn @ v + q @ S ----
    short8 a_at[2];
#pragma unroll
    for (int kk = 0; kk < 2; ++kk)
      a_at[kk] = ld8(&s_at[arow + kk * 32 + lq * 8]);
    f32x4 ao[4] = {zero4, zero4, zero4, zero4};
#pragma unroll
    for (int c = 0; c < 4; ++c) {
      const int br = (c * 16 + lr) * LP;
#pragma unroll
      for (int kk = 0; kk < 2; ++kk) {
        ao[c] = MFMA_B16(a_q[kk],  ld8(&s_Sb[br + kk * 32 + lq * 8]), ao[c]);  // o_inter
        ao[c] = MFMA_B16(a_at[kk], ld8(&s_vT[br + kk * 32 + lq * 8]), ao[c]);  // o_intra
      }
    }
#pragma unroll
    for (int c = 0; c < 4; ++c)
#pragma unroll
      for (int j = 0; j < 4; ++j)
        s_xo[(w * 16 + lq * 4 + j) * LP + c * 16 + lr] = f2bf(ao[c][j]);  // o over xc
    __syncthreads();  // B3

    // ---- stage D: out = o @ Wo -> global fp32 ----
    short8 a_o[2];
#pragma unroll
    for (int kk = 0; kk < 2; ++kk)
      a_o[kk] = ld8(&s_xo[arow + kk * 32 + lq * 8]);
    f32x4 aou[4] = {zero4, zero4, zero4, zero4};
#pragma unroll
    for (int c = 0; c < 4; ++c)
#pragma unroll
      for (int kk = 0; kk < 2; ++kk)
        aou[c] = MFMA_B16(a_o[kk], ld8(woT + (c * 16 + lr) * 64 + kk * 32 + lq * 8), aou[c]);
    float* orow = obase + (size_t)(ci * CHc) * Ec;
#pragma unroll
    for (int c = 0; c < 4; ++c)
#pragma unroll
      for (int j = 0; j < 4; ++j)
        orow[(size_t)(w * 16 + lq * 4 + j) * Ec + c * 16 + lr] = aou[c][j];
    __syncthreads();  // B4 — protect s_xo before next chunk's stage
  }
}

extern "C" void kernel_launch(void* const* d_in, const int* in_sizes, int n_in,
                              void* d_out, int out_size, void* d_ws, size_t ws_size,
                              hipStream_t stream) {
  const float* x  = (const float*)d_in[0];
  const float* Wq = (const float*)d_in[1];
  const float* Wk = (const float*)d_in[2];
  const float* Wv = (const float*)d_in[3];
  const float* Wo = (const float*)d_in[4];
  float* out = (float*)d_out;

  unsigned short* wT = (unsigned short*)d_ws;            // 4 x [64][64] bf16 = 32 KB
  float* kvseg = (float*)((char*)d_ws + 32768);          // [64 bh][4 seg][64][64] fp32 = 4 MB

  prep_weights<<<dim3(64), dim3(256), 0, stream>>>(Wq, Wk, Wv, Wo, wT);
  pass1_kvseg<<<dim3(64, NSEG), dim3(256), 0, stream>>>(x, wT, kvseg);
  pass3_main<<<dim3(64, NSEG), dim3(256), 0, stream>>>(x, wT, kvseg, out);
}